// Round 12
// baseline (1644.533 us; speedup 1.0000x reference)
//
#include <hip/hip_runtime.h>

#define T_ 300
#define C_ 128
#define HB 131072  // byte offset of h double-buffer in k_lstm LDS
#define L2E  1.4426950408889634f
#define L2E2 2.8853900817779268f

typedef _Float16 f16;
typedef _Float16 f16x8 __attribute__((ext_vector_type(8)));
typedef _Float16 f16x4 __attribute__((ext_vector_type(4)));
typedef _Float16 f16x2 __attribute__((ext_vector_type(2)));
typedef float f32x4 __attribute__((ext_vector_type(4)));

#define MFMA16(a, b, c) __builtin_amdgcn_mfma_f32_16x16x32_f16((a), (b), (c), 0, 0, 0)

#if __has_builtin(__builtin_amdgcn_exp2f)
#define EX2(x) __builtin_amdgcn_exp2f(x)
#else
#define EX2(x) exp2f(x)
#endif
#define RCPF(x) __builtin_amdgcn_rcpf(x)

// sigmoid(x) = 1/(1+e^-x) = rcp(1 + 2^(-x*log2e)) — same math __expf/__fdividef
// expand to, minus fixup instructions. tanh(x) = 1 - 2/(1+e^{2x}).
__device__ __forceinline__ float sigm(float x) {
    return RCPF(1.f + EX2(-x * L2E));
}
__device__ __forceinline__ float tanhx(float x) {
    return __builtin_fmaf(-2.f, RCPF(1.f + EX2(x * L2E2)), 1.f);
}

// ---------------- K0: weight conversion / pre-swizzle (UNSCALED — R9 verbatim) ----------------
__global__ void k_prep(const float* __restrict__ Wih, const float* __restrict__ Whh,
                       const float* __restrict__ bih, const float* __restrict__ bhh,
                       f16* __restrict__ wlds, f16* __restrict__ whhswz,
                       f16* __restrict__ wihswz, float* __restrict__ bsum)
{
    int i = blockIdx.x * 256 + threadIdx.x;
    if (i < 8192) {
        int col = i >> 3, k0 = (i & 7) * 8;
#pragma unroll
        for (int j = 0; j < 8; j++) wlds[col * 64 + k0 + j] = (f16)Whh[col * 256 + k0 + j];
    } else if (i < 32768) {
        // W_hh k64..256 pre-swizzled per (w16, g, kfi 0..5, lane)
        int q = i - 8192; int l = q & 63; q >>= 6;
        int kfi = q % 6; q /= 6;
        int g = q & 3, w16 = q >> 2;
        int col = g * 256 + 16 * w16 + (l & 15);
        int k = 64 + kfi * 32 + 8 * (l >> 4);
        f16* dst = whhswz + (((size_t)(w16 * 4 + g) * 6 + kfi) * 64 + l) * 8;
#pragma unroll
        for (int j = 0; j < 8; j++) dst[j] = (f16)Whh[col * 256 + k + j];
    } else if (i < 49152) {
        // W_ih k0..128 pre-swizzled per (w16, g, kfi 0..3, lane)
        int q = i - 32768; int l = q & 63; q >>= 6;
        int kfi = q & 3; q >>= 2;
        int g = q & 3, w16 = q >> 2;
        int col = g * 256 + 16 * w16 + (l & 15);
        int k = kfi * 32 + 8 * (l >> 4);
        f16* dst = wihswz + (((size_t)(w16 * 4 + g) * 4 + kfi) * 64 + l) * 8;
#pragma unroll
        for (int j = 0; j < 8; j++) dst[j] = (f16)Wih[col * 128 + k + j];
    } else if (i < 50176) {
        int j = i - 49152;
        bsum[j] = bih[j] + bhh[j];
    }
}

// ---------------- K1: x_proj precompute (fully parallel — R9 verbatim) ----------------
__global__ __launch_bounds__(1024)
__attribute__((amdgpu_waves_per_eu(4, 4)))
void k_xproj(const float* __restrict__ x, const f16* __restrict__ wihswz,
             const float* __restrict__ bsum, f16* __restrict__ xp,
             int cs, int ce, int CHT)
{
    __shared__ __align__(16) char sd[8192];
    const int tid = threadIdx.x, lane = tid & 63, w = tid >> 6;
    const int sg = blockIdx.x & 15, tb = blockIdx.x >> 4;
    const int c16 = lane & 15, quad = lane >> 4;
    int ss = cs + tb * 8;
    int sse = ss + 8; if (sse > ce) sse = ce;

    f16x8 wreg[16];
#pragma unroll
    for (int g = 0; g < 4; g++)
#pragma unroll
        for (int kfi = 0; kfi < 4; kfi++)
            wreg[g * 4 + kfi] = *(const f16x8*)(wihswz + (((size_t)(w * 4 + g) * 4 + kfi) * 64 + lane) * 8);

    float bs[4];
#pragma unroll
    for (int g = 0; g < 4; g++) bs[g] = bsum[g * 256 + 16 * w + c16];

    for (int s = ss; s < sse; s++) {
        int pb = (s & 1) * 4096;
        {
            int seq = tid >> 6, cb = (tid & 63) * 2;
            const float* xr = x + ((size_t)(sg * 16 + seq) * T_ + s) * C_ + cb;
            float a0 = xr[0], a1 = xr[1], b0 = xr[C_], b1 = xr[C_ + 1];
            f16x2 d2 = {(f16)(b0 - a0), (f16)(b1 - a1)};
            *(f16x2*)(sd + pb + ((seq * 256 + cb * 2) ^ ((seq & 7) << 4))) = d2;
        }
        __syncthreads();
        f32x4 a[4];
#pragma unroll
        for (int g = 0; g < 4; g++) a[g] = (f32x4){0.f, 0.f, 0.f, 0.f};
#pragma unroll
        for (int kf = 0; kf < 4; kf++) {
            f16x8 af = *(const f16x8*)(sd + pb + ((c16 * 256 + (kf * 32 + 8 * quad) * 2) ^ ((c16 & 7) << 4)));
#pragma unroll
            for (int g = 0; g < 4; g++) a[g] = MFMA16(af, wreg[g * 4 + kf], a[g]);
        }
        f16* ob = xp + (((size_t)sg * CHT + (s - cs)) * 16 + w) * 1024 + lane * 4;
#pragma unroll
        for (int g = 0; g < 4; g++) {
            f16x4 o = {(f16)(a[g].x + bs[g]), (f16)(a[g].y + bs[g]),
                       (f16)(a[g].z + bs[g]), (f16)(a[g].w + bs[g])};
            *(f16x4*)(ob + g * 256) = o;
        }
    }
}

// ---------------- K2: recurrence — R9 structure + register-hoisted W-image B-frags ----------------
#define VMW(N)  asm volatile("s_waitcnt vmcnt(" #N ")"); __builtin_amdgcn_sched_barrier(0x186);
#define VMW0(N) asm volatile("s_waitcnt vmcnt(" #N ")"); __builtin_amdgcn_sched_barrier(0);
#define GL(dst, voff, IMM) asm volatile("global_load_dwordx4 %0, %1, %2 offset:" IMM : "=v"(dst) : "v"(voff), "s"(wsz))
#define GLX(dst, IMM)      asm volatile("global_load_dwordx2 %0, %1, off offset:" IMM : "=v"(dst) : "v"(xaddr))
#define ISS_K0() GL(X0,voffA0,"0");    GL(X1,voffA1,"0");    GL(X2,voffA2,"0");    GL(X3,voffA3,"0")
#define ISS_K1() GL(Y0,voffA0,"1024"); GL(Y1,voffA1,"1024"); GL(Y2,voffA2,"1024"); GL(Y3,voffA3,"1024")
#define ISS_K2() GL(Z0,voffA0,"2048"); GL(Z1,voffA1,"2048"); GL(Z2,voffA2,"2048"); GL(Z3,voffA3,"2048")
#define ISS_K3() GL(X0,voffB0,"0");    GL(X1,voffB1,"0");    GL(X2,voffB2,"0");    GL(X3,voffB3,"0")
#define ISS_K4() GL(Y0,voffB0,"1024"); GL(Y1,voffB1,"1024"); GL(Y2,voffB2,"1024"); GL(Y3,voffB3,"1024")
#define ISS_K5() GL(Z0,voffB0,"2048"); GL(Z1,voffB1,"2048"); GL(Z2,voffB2,"2048"); GL(Z3,voffB3,"2048")
#define ISS_XC() GLX(xv0,"0"); GLX(xv1,"512"); GLX(xv2,"1024"); GLX(xv3,"1536")
#define SEC(AFO, B0,B1,B2,B3) { f16x8 af = *(const f16x8*)(rbp + (AFO)); \
    acc0 = MFMA16(af, B0, acc0); acc1 = MFMA16(af, B1, acc1); \
    acc2 = MFMA16(af, B2, acc2); acc3 = MFMA16(af, B3, acc3); }
#define GATES_AND_BARRIER() \
        { \
            _Pragma("unroll") \
            for (int r = 0; r < 4; r++) { \
                float gi = acc0[r], gf = acc1[r], gg = acc2[r], go = acc3[r]; \
                float c_ = sigm(gf) * cst[r] + sigm(gi) * tanhx(gg); \
                cst[r] = c_; \
                float h_ = sigm(go) * tanhx(c_); \
                pool[r] += h_; \
                *(f16*)(wbp + hwo[r]) = (f16)h_; \
            } \
        } \
        asm volatile("s_waitcnt lgkmcnt(0)\n\ts_barrier" ::: "memory");

__global__ __launch_bounds__(1024)
__attribute__((amdgpu_waves_per_eu(4, 4)))
void k_lstm(const f16* __restrict__ wlds_src, const f16* __restrict__ whhswz,
            const float* __restrict__ bsum, const f16* __restrict__ xp,
            float* __restrict__ feat, char* __restrict__ hstate,
            float* __restrict__ cstate, float* __restrict__ poolstate,
            int cs, int ce, int CHT)
{
    __shared__ __align__(16) char lds[147456];
    const int tid = threadIdx.x, lane = tid & 63, w = tid >> 6;
    const int wg = blockIdx.x, win = wg >> 4, sg = wg & 15;
    const int c16 = lane & 15, quad = lane >> 4;
    const int a1 = win ? 299 : 154;
    const int t0 = win ? 145 : 0;
    int s0 = cs > t0 ? cs : t0;
    const int se = ce < 299 ? ce : 299;
    if (s0 >= se) return;
    const bool init = (s0 == t0);
    const f16* wsz = whhswz;

    // stage W k<64 image (swizzled)
    {
        int col = tid;
#pragma unroll
        for (int kb = 0; kb < 8; kb++) {
            f16x8 v = *(const f16x8*)(wlds_src + col * 64 + kb * 8);
            int byte = (col * 128 + kb * 16) ^ ((col & 7) << 4);
            *(f16x8*)(lds + byte) = v;
        }
    }
    // restore / zero h read-slot for step s0
    {
        char* slot = lds + HB + (((s0 - 1) & 1) * 8192);
        if (init) {
            f16x4 z = {0, 0, 0, 0};
            *(f16x4*)(slot + tid * 8) = z;
        } else {
            *(f16x4*)(slot + tid * 8) = *(const f16x4*)(hstate + (size_t)wg * 8192 + tid * 8);
        }
    }

    float bs0 = bsum[0 * 256 + 16 * w + c16];
    float bs1 = bsum[1 * 256 + 16 * w + c16];
    float bs2 = bsum[2 * 256 + 16 * w + c16];
    float bs3 = bsum[3 * 256 + 16 * w + c16];

    float cst[4], pool[4];
    if (init) {
#pragma unroll
        for (int i = 0; i < 4; i++) { cst[i] = 0.f; pool[i] = 0.f; }
    } else {
        const float* cp = cstate + ((size_t)wg * 1024 + tid) * 4;
        const float* pp = poolstate + ((size_t)wg * 1024 + tid) * 4;
#pragma unroll
        for (int i = 0; i < 4; i++) { cst[i] = cp[i]; pool[i] = pp[i]; }
    }

    // loop-invariant offsets
    const int aswz = (c16 & 7) << 4;
    const int abase = c16 * 512;
    int afo[8];
#pragma unroll
    for (int kf = 0; kf < 8; kf++) afo[kf] = (abase + (kf * 32 + 8 * quad) * 2) ^ aswz;
    int bfo[8];
#pragma unroll
    for (int g = 0; g < 4; g++) {
        int col = g * 256 + 16 * w + c16;
        int cswz = (col & 7) << 4;
#pragma unroll
        for (int kf = 0; kf < 2; kf++) bfo[g * 2 + kf] = (col * 128 + (kf * 32 + 8 * quad) * 2) ^ cswz;
    }
    int hwo[4];
#pragma unroll
    for (int r = 0; r < 4; r++) {
        int m = 4 * quad + r;
        hwo[r] = (m * 512 + (16 * w + c16) * 2) ^ ((m & 7) << 4);
    }
    // stream voffsets: byte = (w*4+g)*6144 + kfi*1024 + lane*16
    unsigned voffA0 = (unsigned)((w * 4 + 0) * 6144 + lane * 16);
    unsigned voffA1 = (unsigned)((w * 4 + 1) * 6144 + lane * 16);
    unsigned voffA2 = (unsigned)((w * 4 + 2) * 6144 + lane * 16);
    unsigned voffA3 = (unsigned)((w * 4 + 3) * 6144 + lane * 16);
    unsigned voffB0 = voffA0 + 3072, voffB1 = voffA1 + 3072;
    unsigned voffB2 = voffA2 + 3072, voffB3 = voffA3 + 3072;
    unsigned long long xaddr = (unsigned long long)xp
        + (((unsigned long long)sg * CHT + (unsigned)(s0 - cs)) * 16 + (unsigned)w) * 2048ull
        + (unsigned)lane * 8ull;

    f16x8 X0, X1, X2, X3, Y0, Y1, Y2, Y3, Z0, Z1, Z2, Z3;
    f16x4 xv0, xv1, xv2, xv3;
    float fillv;

    __syncthreads();

    // hoist step-invariant W-image B-fragments (k0..64) into registers.
    // Plain LDS reads: if regs run short the compiler sinks them back = R9.
    f16x8 wbf[8];
#pragma unroll
    for (int i = 0; i < 8; i++) wbf[i] = *(const f16x8*)(lds + bfo[i]);

    const int ae = se < a1 ? se : a1;   // active end
    if (s0 < a1) { ISS_XC(); ISS_K0(); ISS_K1(); ISS_K2(); }

    // ---------------- ACTIVE phase ----------------
    for (int t = s0; t < ae; ++t) {
        const char* rbp = lds + HB + (((t + 1) & 1) << 13);
        char* wbp = lds + HB + ((t & 1) << 13);
        VMW0(12);   // drain xc for this step
        f32x4 acc0 = {(float)xv0.x, (float)xv0.y, (float)xv0.z, (float)xv0.w};
        f32x4 acc1 = {(float)xv1.x, (float)xv1.y, (float)xv1.z, (float)xv1.w};
        f32x4 acc2 = {(float)xv2.x, (float)xv2.y, (float)xv2.z, (float)xv2.w};
        f32x4 acc3 = {(float)xv3.x, (float)xv3.y, (float)xv3.z, (float)xv3.w};
        xaddr += 32768ull;
        ISS_XC();                         // t+1, in flight across barrier
        SEC(afo[0], wbf[0], wbf[2], wbf[4], wbf[6]);      // k0..32
        SEC(afo[1], wbf[1], wbf[3], wbf[5], wbf[7]);      // k32..64
        VMW(12); SEC(afo[2], X0, X1, X2, X3); ISS_K3();   // k64..96
        VMW(12); SEC(afo[3], Y0, Y1, Y2, Y3); ISS_K4();   // k96..128
        VMW(12); SEC(afo[4], Z0, Z1, Z2, Z3); ISS_K5();   // k128..160
        VMW(8);  SEC(afo[5], X0, X1, X2, X3); ISS_K0();   // k160..192
        VMW(8);  SEC(afo[6], Y0, Y1, Y2, Y3); ISS_K1();   // k192..224
        VMW(8);  SEC(afo[7], Z0, Z1, Z2, Z3); ISS_K2();   // k224..256
        GATES_AND_BARRIER();
    }

    // ---------------- IDLE phase (win0 tail: zero input) ----------------
    const int is0 = s0 > a1 ? s0 : a1;
    if (is0 < se && s0 >= a1) { ISS_K0(); ISS_K1(); ISS_K2(); }
    for (int t = is0; t < se; ++t) {
        const char* rbp = lds + HB + (((t + 1) & 1) << 13);
        char* wbp = lds + HB + ((t & 1) << 13);
        f32x4 acc0 = {bs0, bs0, bs0, bs0};
        f32x4 acc1 = {bs1, bs1, bs1, bs1};
        f32x4 acc2 = {bs2, bs2, bs2, bs2};
        f32x4 acc3 = {bs3, bs3, bs3, bs3};
        SEC(afo[0], wbf[0], wbf[2], wbf[4], wbf[6]);
        SEC(afo[1], wbf[1], wbf[3], wbf[5], wbf[7]);
        VMW(12); SEC(afo[2], X0, X1, X2, X3); ISS_K3();
        VMW(12); SEC(afo[3], Y0, Y1, Y2, Y3); ISS_K4();
        VMW(12); SEC(afo[4], Z0, Z1, Z2, Z3); ISS_K5();
        VMW(8);  SEC(afo[5], X0, X1, X2, X3); ISS_K0();
        VMW(8);  SEC(afo[6], Y0, Y1, Y2, Y3); ISS_K1();
        VMW(8);  SEC(afo[7], Z0, Z1, Z2, Z3); ISS_K2();
        GATES_AND_BARRIER();
    }

    if (se < 299) {
        const char* slot = lds + HB + (((se - 1) & 1) * 8192);
        *(f16x4*)(hstate + (size_t)wg * 8192 + tid * 8) = *(const f16x4*)(slot + tid * 8);
        float* cp = cstate + ((size_t)wg * 1024 + tid) * 4;
        float* pp = poolstate + ((size_t)wg * 1024 + tid) * 4;
#pragma unroll
        for (int i = 0; i < 4; i++) { cp[i] = cst[i]; pp[i] = pool[i]; }
    } else {
#pragma unroll
        for (int r = 0; r < 4; r++) {
            int m = 4 * quad + r;
            feat[(size_t)(sg * 16 + m) * 512 + win * 256 + 16 * w + c16] = pool[r];
        }
    }
    (void)fillv;
}

// ---------------- K3: final FC ----------------
__global__ void k_fc(const float* __restrict__ feat, const float* __restrict__ Wfc,
                     const float* __restrict__ bfc, float* __restrict__ out)
{
    int b = blockIdx.x, c = threadIdx.x;
    if (c < 60) {
        const float4* fr = (const float4*)(feat + (size_t)b * 512);
        const float4* wr = (const float4*)(Wfc + (size_t)c * 512);
        float s = bfc[c];
        for (int k = 0; k < 128; k++) {
            float4 f = fr[k], ww = wr[k];
            s += f.x * ww.x + f.y * ww.y + f.z * ww.z + f.w * ww.w;
        }
        out[b * 60 + c] = s;
    }
}

extern "C" void kernel_launch(void* const* d_in, const int* in_sizes, int n_in,
                              void* d_out, int out_size, void* d_ws, size_t ws_size,
                              hipStream_t stream)
{
    const float* x   = (const float*)d_in[0];
    const float* Wih = (const float*)d_in[1];
    const float* Whh = (const float*)d_in[2];
    const float* bih = (const float*)d_in[3];
    const float* bhh = (const float*)d_in[4];
    const float* Wfc = (const float*)d_in[5];
    const float* bfc = (const float*)d_in[6];
    float* out = (float*)d_out;

    char* p = (char*)d_ws;
    f16* wlds    = (f16*)p;   p += 131072;
    f16* whhswz  = (f16*)p;   p += 393216;
    f16* wihswz  = (f16*)p;   p += 262144;
    float* bsum  = (float*)p; p += 4096;
    float* feat  = (float*)p; p += 524288;
    char* hstate = p;         p += 262144;
    float* cstate = (float*)p;    p += 524288;
    float* poolstate = (float*)p; p += 524288;
    f16* xp = (f16*)p;
    size_t fixed = (size_t)(p - (char*)d_ws);

    long long avail = (long long)ws_size - (long long)fixed - 65536;  // prefetch slack
    int CHT = (int)(avail / 524288);
    if (CHT < 1) CHT = 1;
    if (CHT > 299) CHT = 299;

    k_prep<<<196, 256, 0, stream>>>(Wih, Whh, bih, bhh, wlds, whhswz, wihswz, bsum);
    for (int cs = 0; cs < 299; cs += CHT) {
        int ce = cs + CHT; if (ce > 299) ce = 299;
        int nb = (ce - cs + 7) / 8;
        k_xproj<<<16 * nb, 1024, 0, stream>>>(x, wihswz, bsum, xp, cs, ce, CHT);
        k_lstm<<<32, 1024, 0, stream>>>(wlds, whhswz, bsum, xp, feat,
                                        hstate, cstate, poolstate, cs, ce, CHT);
    }
    k_fc<<<256, 64, 0, stream>>>(feat, Wfc, bfc, out);
}

// Round 14
// 1324.184 us; speedup vs baseline: 1.2419x; 1.2419x over previous
//
#include <hip/hip_runtime.h>

#define T_ 300
#define C_ 128
#define HB 131072  // byte offset of h double-buffer in k_lstm LDS

typedef _Float16 f16;
typedef _Float16 f16x8 __attribute__((ext_vector_type(8)));
typedef _Float16 f16x4 __attribute__((ext_vector_type(4)));
typedef _Float16 f16x2 __attribute__((ext_vector_type(2)));
typedef float f32x4 __attribute__((ext_vector_type(4)));

#define MFMA16(a, b, c) __builtin_amdgcn_mfma_f32_16x16x32_f16((a), (b), (c), 0, 0, 0)

__device__ __forceinline__ float sigm(float x) {
    return __fdividef(1.f, 1.f + __expf(-x));
}
__device__ __forceinline__ float tanhx(float x) {
    float e = __expf(2.f * x);
    return __builtin_fmaf(-2.f, __frcp_rn(1.f + e), 1.f);
}

// ---------------- K0: weight conversion / pre-swizzle (R9 verbatim) ----------------
__global__ void k_prep(const float* __restrict__ Wih, const float* __restrict__ Whh,
                       const float* __restrict__ bih, const float* __restrict__ bhh,
                       f16* __restrict__ wlds, f16* __restrict__ whhswz,
                       f16* __restrict__ wihswz, float* __restrict__ bsum)
{
    int i = blockIdx.x * 256 + threadIdx.x;
    if (i < 8192) {
        int col = i >> 3, k0 = (i & 7) * 8;
#pragma unroll
        for (int j = 0; j < 8; j++) wlds[col * 64 + k0 + j] = (f16)Whh[col * 256 + k0 + j];
    } else if (i < 32768) {
        // W_hh k64..256 pre-swizzled per (w16, g, kfi 0..5, lane)
        int q = i - 8192; int l = q & 63; q >>= 6;
        int kfi = q % 6; q /= 6;
        int g = q & 3, w16 = q >> 2;
        int col = g * 256 + 16 * w16 + (l & 15);
        int k = 64 + kfi * 32 + 8 * (l >> 4);
        f16* dst = whhswz + (((size_t)(w16 * 4 + g) * 6 + kfi) * 64 + l) * 8;
#pragma unroll
        for (int j = 0; j < 8; j++) dst[j] = (f16)Whh[col * 256 + k + j];
    } else if (i < 49152) {
        // W_ih k0..128 pre-swizzled per (w16, g, kfi 0..3, lane)
        int q = i - 32768; int l = q & 63; q >>= 6;
        int kfi = q & 3; q >>= 2;
        int g = q & 3, w16 = q >> 2;
        int col = g * 256 + 16 * w16 + (l & 15);
        int k = kfi * 32 + 8 * (l >> 4);
        f16* dst = wihswz + (((size_t)(w16 * 4 + g) * 4 + kfi) * 64 + l) * 8;
#pragma unroll
        for (int j = 0; j < 8; j++) dst[j] = (f16)Wih[col * 128 + k + j];
    } else if (i < 50176) {
        int j = i - 49152;
        bsum[j] = bih[j] + bhh[j];
    }
}

// ---------------- K1: x_proj precompute (R9 verbatim) ----------------
__global__ __launch_bounds__(1024)
__attribute__((amdgpu_waves_per_eu(4, 4)))
void k_xproj(const float* __restrict__ x, const f16* __restrict__ wihswz,
             const float* __restrict__ bsum, f16* __restrict__ xp,
             int cs, int ce, int CHT)
{
    __shared__ __align__(16) char sd[8192];
    const int tid = threadIdx.x, lane = tid & 63, w = tid >> 6;
    const int sg = blockIdx.x & 15, tb = blockIdx.x >> 4;
    const int c16 = lane & 15, quad = lane >> 4;
    int ss = cs + tb * 8;
    int sse = ss + 8; if (sse > ce) sse = ce;

    f16x8 wreg[16];
#pragma unroll
    for (int g = 0; g < 4; g++)
#pragma unroll
        for (int kfi = 0; kfi < 4; kfi++)
            wreg[g * 4 + kfi] = *(const f16x8*)(wihswz + (((size_t)(w * 4 + g) * 4 + kfi) * 64 + lane) * 8);

    float bs[4];
#pragma unroll
    for (int g = 0; g < 4; g++) bs[g] = bsum[g * 256 + 16 * w + c16];

    for (int s = ss; s < sse; s++) {
        int pb = (s & 1) * 4096;
        {
            int seq = tid >> 6, cb = (tid & 63) * 2;
            const float* xr = x + ((size_t)(sg * 16 + seq) * T_ + s) * C_ + cb;
            float a0 = xr[0], a1 = xr[1], b0 = xr[C_], b1 = xr[C_ + 1];
            f16x2 d2 = {(f16)(b0 - a0), (f16)(b1 - a1)};
            *(f16x2*)(sd + pb + ((seq * 256 + cb * 2) ^ ((seq & 7) << 4))) = d2;
        }
        __syncthreads();
        f32x4 a[4];
#pragma unroll
        for (int g = 0; g < 4; g++) a[g] = (f32x4){0.f, 0.f, 0.f, 0.f};
#pragma unroll
        for (int kf = 0; kf < 4; kf++) {
            f16x8 af = *(const f16x8*)(sd + pb + ((c16 * 256 + (kf * 32 + 8 * quad) * 2) ^ ((c16 & 7) << 4)));
#pragma unroll
            for (int g = 0; g < 4; g++) a[g] = MFMA16(af, wreg[g * 4 + kf], a[g]);
        }
        f16* ob = xp + (((size_t)sg * CHT + (s - cs)) * 16 + w) * 1024 + lane * 4;
#pragma unroll
        for (int g = 0; g < 4; g++) {
            f16x4 o = {(f16)(a[g].x + bs[g]), (f16)(a[g].y + bs[g]),
                       (f16)(a[g].z + bs[g]), (f16)(a[g].w + bs[g])};
            *(f16x4*)(ob + g * 256) = o;
        }
    }
}

// ---------------- K2: recurrence — R9 + 2 resident kfi, 4 streamed rounds ----------------
// Register envelope (hard-learned R10/11/13): stream bufs + resident <= 64 regs.
// Resident W2*/W3* (kfi0,1 = k64..128): asm loads drained by vmcnt(0) BEFORE the
// loop (outside the counted ledger). Streams kfi2..5 in X/Y buffers.
// Ledger (active), queue oldest->newest, 4 loads per ISS:
//   top: [X:kfi2, Y:kfi3] = 8 ; VMW0(8) no-op (first iter: retires xc)
//   ISS_XC -> [X,Y,xc]=12
//   (image + resident sections ~800cyc shadow)
//   VMW(8)->retire X ; SEC kf4 ; ISS_X4 -> [Y,xc,X4]=12
//   VMW(8)->retire Y ; SEC kf5 ; ISS_Y5 -> [xc,X4,Y5]=12
//   VMW(4)->retire xc+X4 ; SEC kf6 ; ISS_X2 -> [Y5,X2]=8
//   VMW(4)->retire Y5 ; SEC kf7 ; ISS_Y3 -> [X2,Y3]=8
#define VMW8()   asm volatile("s_waitcnt vmcnt(8)");  __builtin_amdgcn_sched_barrier(0x186);
#define VMW4()   asm volatile("s_waitcnt vmcnt(4)");  __builtin_amdgcn_sched_barrier(0x186);
#define VMW0_8() asm volatile("s_waitcnt vmcnt(8)");  __builtin_amdgcn_sched_barrier(0);
#define GL(dst, voff, IMM) asm volatile("global_load_dwordx4 %0, %1, %2 offset:" IMM : "=v"(dst) : "v"(voff), "s"(wsz))
#define GLR(dst, voff, IMM) asm volatile("global_load_dwordx4 %0, %1, %2 offset:" IMM : "=&v"(dst) : "v"(voff), "s"(wsz))
#define GLX(dst, IMM)      asm volatile("global_load_dwordx2 %0, %1, off offset:" IMM : "=v"(dst) : "v"(xaddr))
#define ISS_X2() GL(X0,voffB0,"0");    GL(X1,voffB1,"0");    GL(X2,voffB2,"0");    GL(X3,voffB3,"0")
#define ISS_Y3() GL(Y0,voffB0,"1024"); GL(Y1,voffB1,"1024"); GL(Y2,voffB2,"1024"); GL(Y3,voffB3,"1024")
#define ISS_X4() GL(X0,voffB0,"2048"); GL(X1,voffB1,"2048"); GL(X2,voffB2,"2048"); GL(X3,voffB3,"2048")
#define ISS_Y5() GL(Y0,voffB0,"3072"); GL(Y1,voffB1,"3072"); GL(Y2,voffB2,"3072"); GL(Y3,voffB3,"3072")
#define ISS_XC() GLX(xv0,"0"); GLX(xv1,"512"); GLX(xv2,"1024"); GLX(xv3,"1536")
#define SEC(AFO, B0,B1,B2,B3) { f16x8 af = *(const f16x8*)(rbp + (AFO)); \
    acc0 = MFMA16(af, B0, acc0); acc1 = MFMA16(af, B1, acc1); \
    acc2 = MFMA16(af, B2, acc2); acc3 = MFMA16(af, B3, acc3); }
#define SECIMG(AFO, O0,O1,O2,O3) { f16x8 af = *(const f16x8*)(rbp + (AFO)); \
    { f16x8 b = *(const f16x8*)(lds + (O0)); acc0 = MFMA16(af, b, acc0); } \
    { f16x8 b = *(const f16x8*)(lds + (O1)); acc1 = MFMA16(af, b, acc1); } \
    { f16x8 b = *(const f16x8*)(lds + (O2)); acc2 = MFMA16(af, b, acc2); } \
    { f16x8 b = *(const f16x8*)(lds + (O3)); acc3 = MFMA16(af, b, acc3); } }
#define GATES_AND_BARRIER() \
        { \
            _Pragma("unroll") \
            for (int r = 0; r < 4; r++) { \
                float gi = acc0[r], gf = acc1[r], gg = acc2[r], go = acc3[r]; \
                float c_ = sigm(gf) * cst[r] + sigm(gi) * tanhx(gg); \
                cst[r] = c_; \
                float h_ = sigm(go) * tanhx(c_); \
                pool[r] += h_; \
                *(f16*)(wbp + hwo[r]) = (f16)h_; \
            } \
        } \
        asm volatile("s_waitcnt lgkmcnt(0)\n\ts_barrier" ::: "memory");

__global__ __launch_bounds__(1024)
__attribute__((amdgpu_waves_per_eu(4, 4)))
void k_lstm(const f16* __restrict__ wlds_src, const f16* __restrict__ whhswz,
            const float* __restrict__ bsum, const f16* __restrict__ xp,
            float* __restrict__ feat, char* __restrict__ hstate,
            float* __restrict__ cstate, float* __restrict__ poolstate,
            int cs, int ce, int CHT)
{
    __shared__ __align__(16) char lds[147456];
    const int tid = threadIdx.x, lane = tid & 63, w = tid >> 6;
    const int wg = blockIdx.x, win = wg >> 4, sg = wg & 15;
    const int c16 = lane & 15, quad = lane >> 4;
    const int a1 = win ? 299 : 154;
    const int t0 = win ? 145 : 0;
    int s0 = cs > t0 ? cs : t0;
    const int se = ce < 299 ? ce : 299;
    if (s0 >= se) return;
    const bool init = (s0 == t0);
    const f16* wsz = whhswz;

    // fragment addresses: frag(w,g,kfi) at (w*4+g)*6144 + kfi*1024 + lane*16
    unsigned voffA0 = (unsigned)((w * 4 + 0) * 6144 + lane * 16);
    unsigned voffA1 = (unsigned)((w * 4 + 1) * 6144 + lane * 16);
    unsigned voffA2 = (unsigned)((w * 4 + 2) * 6144 + lane * 16);
    unsigned voffA3 = (unsigned)((w * 4 + 3) * 6144 + lane * 16);
    unsigned voffB0 = voffA0 + 2048, voffB1 = voffA1 + 2048;   // kfi2 base
    unsigned voffB2 = voffA2 + 2048, voffB3 = voffA3 + 2048;

    // resident W_hh kfi0,1 (k64..128): issued now, drained by vmcnt(0) below,
    // so they never enter the counted in-loop ledger. Earlyclobber outputs.
    f16x8 W20, W21, W22, W23, W30, W31, W32, W33;
    GLR(W20, voffA0, "0");    GLR(W21, voffA1, "0");
    GLR(W22, voffA2, "0");    GLR(W23, voffA3, "0");
    GLR(W30, voffA0, "1024"); GLR(W31, voffA1, "1024");
    GLR(W32, voffA2, "1024"); GLR(W33, voffA3, "1024");

    // stage W k<64 image (swizzled)
    {
        int col = tid;
#pragma unroll
        for (int kb = 0; kb < 8; kb++) {
            f16x8 v = *(const f16x8*)(wlds_src + col * 64 + kb * 8);
            int byte = (col * 128 + kb * 16) ^ ((col & 7) << 4);
            *(f16x8*)(lds + byte) = v;
        }
    }
    // restore / zero h read-slot for step s0
    {
        char* slot = lds + HB + (((s0 - 1) & 1) * 8192);
        if (init) {
            f16x4 z = {0, 0, 0, 0};
            *(f16x4*)(slot + tid * 8) = z;
        } else {
            *(f16x4*)(slot + tid * 8) = *(const f16x4*)(hstate + (size_t)wg * 8192 + tid * 8);
        }
    }

    float cst[4], pool[4];
    if (init) {
#pragma unroll
        for (int i = 0; i < 4; i++) { cst[i] = 0.f; pool[i] = 0.f; }
    } else {
        const float* cp = cstate + ((size_t)wg * 1024 + tid) * 4;
        const float* pp = poolstate + ((size_t)wg * 1024 + tid) * 4;
#pragma unroll
        for (int i = 0; i < 4; i++) { cst[i] = cp[i]; pool[i] = pp[i]; }
    }

    // loop-invariant offsets, compressed (XOR algebra verified):
    // afo[kf] = afo0 + d64*(kf&1) + 128*(kf>>1); bfo[g][kf] = bfog[g] + d64*kf
    const int aswz = (c16 & 7) << 4;
    const int d64 = (aswz & 0x40) ? -64 : 64;
    const int afo0 = (c16 * 512 + 16 * quad) ^ aswz;
    const int afo1 = afo0 + d64;
    int bfog[4];
#pragma unroll
    for (int g = 0; g < 4; g++)
        bfog[g] = ((g * 256 + 16 * w + c16) * 128 + 16 * quad) ^ aswz;
    int hwo[4];
#pragma unroll
    for (int r = 0; r < 4; r++) {
        int m = 4 * quad + r;
        hwo[r] = (m * 512 + (16 * w + c16) * 2) ^ ((m & 7) << 4);
    }

    unsigned long long xaddr = (unsigned long long)xp
        + (((unsigned long long)sg * CHT + (unsigned)(s0 - cs)) * 16 + (unsigned)w) * 2048ull
        + (unsigned)lane * 8ull;

    f16x8 X0, X1, X2, X3, Y0, Y1, Y2, Y3;
    f16x4 xv0, xv1, xv2, xv3;

    // drain resident loads + LDS staging before the pipelined loop
    asm volatile("s_waitcnt vmcnt(0)");
    __builtin_amdgcn_sched_barrier(0);
    __syncthreads();

    const int ae = se < a1 ? se : a1;   // active end
    if (s0 < a1) { ISS_XC(); ISS_X2(); ISS_Y3(); }   // [xc,X,Y]=12

    // ---------------- ACTIVE phase ----------------
    for (int t = s0; t < ae; ++t) {
        const char* rbp = lds + HB + (((t + 1) & 1) << 13);
        char* wbp = lds + HB + ((t & 1) << 13);
        VMW0_8();   // first iter: retire xc; steady state: no-op (xv valid)
        f32x4 acc0 = {(float)xv0.x, (float)xv0.y, (float)xv0.z, (float)xv0.w};
        f32x4 acc1 = {(float)xv1.x, (float)xv1.y, (float)xv1.z, (float)xv1.w};
        f32x4 acc2 = {(float)xv2.x, (float)xv2.y, (float)xv2.z, (float)xv2.w};
        f32x4 acc3 = {(float)xv3.x, (float)xv3.y, (float)xv3.z, (float)xv3.w};
        xaddr += 32768ull;
        ISS_XC();                                           // xc for t+1
        SECIMG(afo0, bfog[0], bfog[1], bfog[2], bfog[3]);                          // kf0
        SECIMG(afo1, bfog[0] + d64, bfog[1] + d64, bfog[2] + d64, bfog[3] + d64);  // kf1
        SEC(afo0 + 128, W20, W21, W22, W23);                // kf2 (resident)
        SEC(afo1 + 128, W30, W31, W32, W33);                // kf3 (resident)
        VMW8(); SEC(afo0 + 256, X0, X1, X2, X3); ISS_X4();  // kf4 <- kfi2
        VMW8(); SEC(afo1 + 256, Y0, Y1, Y2, Y3); ISS_Y5();  // kf5 <- kfi3
        VMW4(); SEC(afo0 + 384, X0, X1, X2, X3); ISS_X2();  // kf6 <- kfi4
        VMW4(); SEC(afo1 + 384, Y0, Y1, Y2, Y3); ISS_Y3();  // kf7 <- kfi5
        GATES_AND_BARRIER();
    }

    // ---------------- IDLE phase (win0 tail: zero input) ----------------
    const int is0 = s0 > a1 ? s0 : a1;
    if (is0 < se) {
        if (s0 >= a1) { ISS_X2(); ISS_Y3(); }   // idle-only chunk: prime [X,Y]=8
        float bs0 = bsum[16 * w + c16];
        float bs1 = bsum[256 + 16 * w + c16];
        float bs2 = bsum[512 + 16 * w + c16];
        float bs3 = bsum[768 + 16 * w + c16];
        for (int t = is0; t < se; ++t) {
            const char* rbp = lds + HB + (((t + 1) & 1) << 13);
            char* wbp = lds + HB + ((t & 1) << 13);
            f32x4 acc0 = {bs0, bs0, bs0, bs0};
            f32x4 acc1 = {bs1, bs1, bs1, bs1};
            f32x4 acc2 = {bs2, bs2, bs2, bs2};
            f32x4 acc3 = {bs3, bs3, bs3, bs3};
            SECIMG(afo0, bfog[0], bfog[1], bfog[2], bfog[3]);
            SECIMG(afo1, bfog[0] + d64, bfog[1] + d64, bfog[2] + d64, bfog[3] + d64);
            SEC(afo0 + 128, W20, W21, W22, W23);
            SEC(afo1 + 128, W30, W31, W32, W33);
            VMW4(); SEC(afo0 + 256, X0, X1, X2, X3); ISS_X4();
            VMW4(); SEC(afo1 + 256, Y0, Y1, Y2, Y3); ISS_Y5();
            VMW4(); SEC(afo0 + 384, X0, X1, X2, X3); ISS_X2();
            VMW4(); SEC(afo1 + 384, Y0, Y1, Y2, Y3); ISS_Y3();
            GATES_AND_BARRIER();
        }
    }

    if (se < 299) {
        const char* slot = lds + HB + (((se - 1) & 1) * 8192);
        *(f16x4*)(hstate + (size_t)wg * 8192 + tid * 8) = *(const f16x4*)(slot + tid * 8);
        float* cp = cstate + ((size_t)wg * 1024 + tid) * 4;
        float* pp = poolstate + ((size_t)wg * 1024 + tid) * 4;
#pragma unroll
        for (int i = 0; i < 4; i++) { cp[i] = cst[i]; pp[i] = pool[i]; }
    } else {
#pragma unroll
        for (int r = 0; r < 4; r++) {
            int m = 4 * quad + r;
            feat[(size_t)(sg * 16 + m) * 512 + win * 256 + 16 * w + c16] = pool[r];
        }
    }
}

// ---------------- K3: final FC ----------------
__global__ void k_fc(const float* __restrict__ feat, const float* __restrict__ Wfc,
                     const float* __restrict__ bfc, float* __restrict__ out)
{
    int b = blockIdx.x, c = threadIdx.x;
    if (c < 60) {
        const float4* fr = (const float4*)(feat + (size_t)b * 512);
        const float4* wr = (const float4*)(Wfc + (size_t)c * 512);
        float s = bfc[c];
        for (int k = 0; k < 128; k++) {
            float4 f = fr[k], ww = wr[k];
            s += f.x * ww.x + f.y * ww.y + f.z * ww.z + f.w * ww.w;
        }
        out[b * 60 + c] = s;
    }
}

extern "C" void kernel_launch(void* const* d_in, const int* in_sizes, int n_in,
                              void* d_out, int out_size, void* d_ws, size_t ws_size,
                              hipStream_t stream)
{
    const float* x   = (const float*)d_in[0];
    const float* Wih = (const float*)d_in[1];
    const float* Whh = (const float*)d_in[2];
    const float* bih = (const float*)d_in[3];
    const float* bhh = (const float*)d_in[4];
    const float* Wfc = (const float*)d_in[5];
    const float* bfc = (const float*)d_in[6];
    float* out = (float*)d_out;

    char* p = (char*)d_ws;
    f16* wlds    = (f16*)p;   p += 131072;
    f16* whhswz  = (f16*)p;   p += 393216;
    f16* wihswz  = (f16*)p;   p += 262144;
    float* bsum  = (float*)p; p += 4096;
    float* feat  = (float*)p; p += 524288;
    char* hstate = p;         p += 262144;
    float* cstate = (float*)p;    p += 524288;
    float* poolstate = (float*)p; p += 524288;
    f16* xp = (f16*)p;
    size_t fixed = (size_t)(p - (char*)d_ws);

    long long avail = (long long)ws_size - (long long)fixed - 65536;  // prefetch slack
    int CHT = (int)(avail / 524288);
    if (CHT < 1) CHT = 1;
    if (CHT > 299) CHT = 299;

    k_prep<<<196, 256, 0, stream>>>(Wih, Whh, bih, bhh, wlds, whhswz, wihswz, bsum);
    for (int cs = 0; cs < 299; cs += CHT) {
        int ce = cs + CHT; if (ce > 299) ce = 299;
        int nb = (ce - cs + 7) / 8;
        k_xproj<<<16 * nb, 1024, 0, stream>>>(x, wihswz, bsum, xp, cs, ce, CHT);
        k_lstm<<<32, 1024, 0, stream>>>(wlds, whhswz, bsum, xp, feat,
                                        hstate, cstate, poolstate, cs, ce, CHT);
    }
    k_fc<<<256, 64, 0, stream>>>(feat, Wfc, bfc, out);
}

// Round 15
// 1097.903 us; speedup vs baseline: 1.4979x; 1.2061x over previous
//
#include <hip/hip_runtime.h>

#define T_ 300
#define C_ 128
#define HB 131072  // byte offset of h double-buffer in k_lstm LDS
#define L2E  1.4426950408889634f
#define L2E2 2.8853900817779268f

typedef _Float16 f16;
typedef _Float16 f16x8 __attribute__((ext_vector_type(8)));
typedef _Float16 f16x4 __attribute__((ext_vector_type(4)));
typedef _Float16 f16x2 __attribute__((ext_vector_type(2)));
typedef float f32x4 __attribute__((ext_vector_type(4)));

#define MFMA16(a, b, c) __builtin_amdgcn_mfma_f32_16x16x32_f16((a), (b), (c), 0, 0, 0)

#if __has_builtin(__builtin_amdgcn_exp2f)
#define EX2(x) __builtin_amdgcn_exp2f(x)
#else
#define EX2(x) exp2f(x)
#endif
#define RCPF(x) __builtin_amdgcn_rcpf(x)

// R12-validated fast forms (absmax 0.03125 there):
// sigmoid(x) = rcp(1 + 2^(-x*log2e)); tanh(x) = 1 - 2*rcp(1 + 2^(x*2log2e))
__device__ __forceinline__ float sigm(float x) {
    return RCPF(1.f + EX2(-x * L2E));
}
__device__ __forceinline__ float tanhx(float x) {
    return __builtin_fmaf(-2.f, RCPF(1.f + EX2(x * L2E2)), 1.f);
}

// ---------------- K0: weight conversion / pre-swizzle (R9 verbatim) ----------------
__global__ void k_prep(const float* __restrict__ Wih, const float* __restrict__ Whh,
                       const float* __restrict__ bih, const float* __restrict__ bhh,
                       f16* __restrict__ wlds, f16* __restrict__ whhswz,
                       f16* __restrict__ wihswz, float* __restrict__ bsum)
{
    int i = blockIdx.x * 256 + threadIdx.x;
    if (i < 8192) {
        int col = i >> 3, k0 = (i & 7) * 8;
#pragma unroll
        for (int j = 0; j < 8; j++) wlds[col * 64 + k0 + j] = (f16)Whh[col * 256 + k0 + j];
    } else if (i < 32768) {
        // W_hh k64..256 pre-swizzled per (w16, g, kfi 0..5, lane)
        int q = i - 8192; int l = q & 63; q >>= 6;
        int kfi = q % 6; q /= 6;
        int g = q & 3, w16 = q >> 2;
        int col = g * 256 + 16 * w16 + (l & 15);
        int k = 64 + kfi * 32 + 8 * (l >> 4);
        f16* dst = whhswz + (((size_t)(w16 * 4 + g) * 6 + kfi) * 64 + l) * 8;
#pragma unroll
        for (int j = 0; j < 8; j++) dst[j] = (f16)Whh[col * 256 + k + j];
    } else if (i < 49152) {
        // W_ih k0..128 pre-swizzled per (w16, g, kfi 0..3, lane)
        int q = i - 32768; int l = q & 63; q >>= 6;
        int kfi = q & 3; q >>= 2;
        int g = q & 3, w16 = q >> 2;
        int col = g * 256 + 16 * w16 + (l & 15);
        int k = kfi * 32 + 8 * (l >> 4);
        f16* dst = wihswz + (((size_t)(w16 * 4 + g) * 4 + kfi) * 64 + l) * 8;
#pragma unroll
        for (int j = 0; j < 8; j++) dst[j] = (f16)Wih[col * 128 + k + j];
    } else if (i < 50176) {
        int j = i - 49152;
        bsum[j] = bih[j] + bhh[j];
    }
}

// ---------------- K1: x_proj precompute (R9 verbatim) ----------------
__global__ __launch_bounds__(1024)
__attribute__((amdgpu_waves_per_eu(4, 4)))
void k_xproj(const float* __restrict__ x, const f16* __restrict__ wihswz,
             const float* __restrict__ bsum, f16* __restrict__ xp,
             int cs, int ce, int CHT)
{
    __shared__ __align__(16) char sd[8192];
    const int tid = threadIdx.x, lane = tid & 63, w = tid >> 6;
    const int sg = blockIdx.x & 15, tb = blockIdx.x >> 4;
    const int c16 = lane & 15, quad = lane >> 4;
    int ss = cs + tb * 8;
    int sse = ss + 8; if (sse > ce) sse = ce;

    f16x8 wreg[16];
#pragma unroll
    for (int g = 0; g < 4; g++)
#pragma unroll
        for (int kfi = 0; kfi < 4; kfi++)
            wreg[g * 4 + kfi] = *(const f16x8*)(wihswz + (((size_t)(w * 4 + g) * 4 + kfi) * 64 + lane) * 8);

    float bs[4];
#pragma unroll
    for (int g = 0; g < 4; g++) bs[g] = bsum[g * 256 + 16 * w + c16];

    for (int s = ss; s < sse; s++) {
        int pb = (s & 1) * 4096;
        {
            int seq = tid >> 6, cb = (tid & 63) * 2;
            const float* xr = x + ((size_t)(sg * 16 + seq) * T_ + s) * C_ + cb;
            float a0 = xr[0], a1 = xr[1], b0 = xr[C_], b1 = xr[C_ + 1];
            f16x2 d2 = {(f16)(b0 - a0), (f16)(b1 - a1)};
            *(f16x2*)(sd + pb + ((seq * 256 + cb * 2) ^ ((seq & 7) << 4))) = d2;
        }
        __syncthreads();
        f32x4 a[4];
#pragma unroll
        for (int g = 0; g < 4; g++) a[g] = (f32x4){0.f, 0.f, 0.f, 0.f};
#pragma unroll
        for (int kf = 0; kf < 4; kf++) {
            f16x8 af = *(const f16x8*)(sd + pb + ((c16 * 256 + (kf * 32 + 8 * quad) * 2) ^ ((c16 & 7) << 4)));
#pragma unroll
            for (int g = 0; g < 4; g++) a[g] = MFMA16(af, wreg[g * 4 + kf], a[g]);
        }
        f16* ob = xp + (((size_t)sg * CHT + (s - cs)) * 16 + w) * 1024 + lane * 4;
#pragma unroll
        for (int g = 0; g < 4; g++) {
            f16x4 o = {(f16)(a[g].x + bs[g]), (f16)(a[g].y + bs[g]),
                       (f16)(a[g].z + bs[g]), (f16)(a[g].w + bs[g])};
            *(f16x4*)(ob + g * 256) = o;
        }
    }
}

// ---------------- K2: recurrence — R14 structure, xc-safe ledger + fast gates ----------------
// Resident W2*/W3* (kfi0,1) drained pre-loop (outside the ledger). Streams kfi2..5.
// Active ledger (queue oldest->newest, 4 loads per ISS):
//   top: [xc, X:kfi2, Y:kfi3] = 12 ; VMW0_8 -> retire xc
//   (image kf0,kf1 + resident kf2,kf3 sections ~shadow)
//   VMW4 -> retire X ; SEC kf4 ; ISS_X4 -> [Y,X4]=8
//   VMW4 -> retire Y ; SEC kf5 ; ISS_Y5 -> [X4,Y5]=8
//   ISS_XC (t+1)                      -> [X4,Y5,xc]=12
//   VMW8 -> retire X4 ; SEC kf6 ; ISS_X2 -> [Y5,xc,X2]=12
//   VMW8 -> retire Y5 ; SEC kf7 ; ISS_Y3 -> [xc,X2,Y3]=12  (matches top)
// xc is never covered by a mid-step wait (it retires only at next step's top).
#define VMW8()   asm volatile("s_waitcnt vmcnt(8)");  __builtin_amdgcn_sched_barrier(0x186);
#define VMW4()   asm volatile("s_waitcnt vmcnt(4)");  __builtin_amdgcn_sched_barrier(0x186);
#define VMW0_8() asm volatile("s_waitcnt vmcnt(8)");  __builtin_amdgcn_sched_barrier(0);
#define GL(dst, voff, IMM) asm volatile("global_load_dwordx4 %0, %1, %2 offset:" IMM : "=v"(dst) : "v"(voff), "s"(wsz))
#define GLR(dst, voff, IMM) asm volatile("global_load_dwordx4 %0, %1, %2 offset:" IMM : "=&v"(dst) : "v"(voff), "s"(wsz))
#define GLX(dst, IMM)      asm volatile("global_load_dwordx2 %0, %1, off offset:" IMM : "=v"(dst) : "v"(xaddr))
#define ISS_X2() GL(X0,voffB0,"0");    GL(X1,voffB1,"0");    GL(X2,voffB2,"0");    GL(X3,voffB3,"0")
#define ISS_Y3() GL(Y0,voffB0,"1024"); GL(Y1,voffB1,"1024"); GL(Y2,voffB2,"1024"); GL(Y3,voffB3,"1024")
#define ISS_X4() GL(X0,voffB0,"2048"); GL(X1,voffB1,"2048"); GL(X2,voffB2,"2048"); GL(X3,voffB3,"2048")
#define ISS_Y5() GL(Y0,voffB0,"3072"); GL(Y1,voffB1,"3072"); GL(Y2,voffB2,"3072"); GL(Y3,voffB3,"3072")
#define ISS_XC() GLX(xv0,"0"); GLX(xv1,"512"); GLX(xv2,"1024"); GLX(xv3,"1536")
#define SEC(AFO, B0,B1,B2,B3) { f16x8 af = *(const f16x8*)(rbp + (AFO)); \
    acc0 = MFMA16(af, B0, acc0); acc1 = MFMA16(af, B1, acc1); \
    acc2 = MFMA16(af, B2, acc2); acc3 = MFMA16(af, B3, acc3); }
#define SECIMG(AFO, O0,O1,O2,O3) { f16x8 af = *(const f16x8*)(rbp + (AFO)); \
    { f16x8 b = *(const f16x8*)(lds + (O0)); acc0 = MFMA16(af, b, acc0); } \
    { f16x8 b = *(const f16x8*)(lds + (O1)); acc1 = MFMA16(af, b, acc1); } \
    { f16x8 b = *(const f16x8*)(lds + (O2)); acc2 = MFMA16(af, b, acc2); } \
    { f16x8 b = *(const f16x8*)(lds + (O3)); acc3 = MFMA16(af, b, acc3); } }
#define GATES_AND_BARRIER() \
        { \
            _Pragma("unroll") \
            for (int r = 0; r < 4; r++) { \
                float gi = acc0[r], gf = acc1[r], gg = acc2[r], go = acc3[r]; \
                float c_ = sigm(gf) * cst[r] + sigm(gi) * tanhx(gg); \
                cst[r] = c_; \
                float h_ = sigm(go) * tanhx(c_); \
                pool[r] += h_; \
                *(f16*)(wbp + hwo[r]) = (f16)h_; \
            } \
        } \
        asm volatile("s_waitcnt lgkmcnt(0)\n\ts_barrier" ::: "memory");

__global__ __launch_bounds__(1024)
__attribute__((amdgpu_waves_per_eu(4, 4)))
void k_lstm(const f16* __restrict__ wlds_src, const f16* __restrict__ whhswz,
            const float* __restrict__ bsum, const f16* __restrict__ xp,
            float* __restrict__ feat, char* __restrict__ hstate,
            float* __restrict__ cstate, float* __restrict__ poolstate,
            int cs, int ce, int CHT)
{
    __shared__ __align__(16) char lds[147456];
    const int tid = threadIdx.x, lane = tid & 63, w = tid >> 6;
    const int wg = blockIdx.x, win = wg >> 4, sg = wg & 15;
    const int c16 = lane & 15, quad = lane >> 4;
    const int a1 = win ? 299 : 154;
    const int t0 = win ? 145 : 0;
    int s0 = cs > t0 ? cs : t0;
    const int se = ce < 299 ? ce : 299;
    if (s0 >= se) return;
    const bool init = (s0 == t0);
    const f16* wsz = whhswz;

    // fragment addresses: frag(w,g,kfi) at (w*4+g)*6144 + kfi*1024 + lane*16
    unsigned voffA0 = (unsigned)((w * 4 + 0) * 6144 + lane * 16);
    unsigned voffA1 = (unsigned)((w * 4 + 1) * 6144 + lane * 16);
    unsigned voffA2 = (unsigned)((w * 4 + 2) * 6144 + lane * 16);
    unsigned voffA3 = (unsigned)((w * 4 + 3) * 6144 + lane * 16);
    unsigned voffB0 = voffA0 + 2048, voffB1 = voffA1 + 2048;   // kfi2 base
    unsigned voffB2 = voffA2 + 2048, voffB3 = voffA3 + 2048;

    // resident W_hh kfi0,1 (k64..128): issued now, drained by vmcnt(0) below,
    // so they never enter the counted in-loop ledger. Earlyclobber outputs.
    f16x8 W20, W21, W22, W23, W30, W31, W32, W33;
    GLR(W20, voffA0, "0");    GLR(W21, voffA1, "0");
    GLR(W22, voffA2, "0");    GLR(W23, voffA3, "0");
    GLR(W30, voffA0, "1024"); GLR(W31, voffA1, "1024");
    GLR(W32, voffA2, "1024"); GLR(W33, voffA3, "1024");

    // stage W k<64 image (swizzled)
    {
        int col = tid;
#pragma unroll
        for (int kb = 0; kb < 8; kb++) {
            f16x8 v = *(const f16x8*)(wlds_src + col * 64 + kb * 8);
            int byte = (col * 128 + kb * 16) ^ ((col & 7) << 4);
            *(f16x8*)(lds + byte) = v;
        }
    }
    // restore / zero h read-slot for step s0
    {
        char* slot = lds + HB + (((s0 - 1) & 1) * 8192);
        if (init) {
            f16x4 z = {0, 0, 0, 0};
            *(f16x4*)(slot + tid * 8) = z;
        } else {
            *(f16x4*)(slot + tid * 8) = *(const f16x4*)(hstate + (size_t)wg * 8192 + tid * 8);
        }
    }

    float cst[4], pool[4];
    if (init) {
#pragma unroll
        for (int i = 0; i < 4; i++) { cst[i] = 0.f; pool[i] = 0.f; }
    } else {
        const float* cp = cstate + ((size_t)wg * 1024 + tid) * 4;
        const float* pp = poolstate + ((size_t)wg * 1024 + tid) * 4;
#pragma unroll
        for (int i = 0; i < 4; i++) { cst[i] = cp[i]; pool[i] = pp[i]; }
    }

    // loop-invariant offsets (XOR algebra verified):
    const int aswz = (c16 & 7) << 4;
    const int d64 = (aswz & 0x40) ? -64 : 64;
    const int afo0 = (c16 * 512 + 16 * quad) ^ aswz;
    const int afo1 = afo0 + d64;
    int bfog[4];
#pragma unroll
    for (int g = 0; g < 4; g++)
        bfog[g] = ((g * 256 + 16 * w + c16) * 128 + 16 * quad) ^ aswz;
    int hwo[4];
#pragma unroll
    for (int r = 0; r < 4; r++) {
        int m = 4 * quad + r;
        hwo[r] = (m * 512 + (16 * w + c16) * 2) ^ ((m & 7) << 4);
    }

    unsigned long long xaddr = (unsigned long long)xp
        + (((unsigned long long)sg * CHT + (unsigned)(s0 - cs)) * 16 + (unsigned)w) * 2048ull
        + (unsigned)lane * 8ull;

    f16x8 X0, X1, X2, X3, Y0, Y1, Y2, Y3;
    f16x4 xv0, xv1, xv2, xv3;

    // drain resident loads + LDS staging before the pipelined loop
    asm volatile("s_waitcnt vmcnt(0)");
    __builtin_amdgcn_sched_barrier(0);
    __syncthreads();

    const int ae = se < a1 ? se : a1;   // active end
    if (s0 < a1) { ISS_XC(); ISS_X2(); ISS_Y3(); }   // [xc,X,Y]=12

    // ---------------- ACTIVE phase ----------------
    for (int t = s0; t < ae; ++t) {
        const char* rbp = lds + HB + (((t + 1) & 1) << 13);
        char* wbp = lds + HB + ((t & 1) << 13);
        VMW0_8();   // retire xc for this step
        f32x4 acc0 = {(float)xv0.x, (float)xv0.y, (float)xv0.z, (float)xv0.w};
        f32x4 acc1 = {(float)xv1.x, (float)xv1.y, (float)xv1.z, (float)xv1.w};
        f32x4 acc2 = {(float)xv2.x, (float)xv2.y, (float)xv2.z, (float)xv2.w};
        f32x4 acc3 = {(float)xv3.x, (float)xv3.y, (float)xv3.z, (float)xv3.w};
        SECIMG(afo0, bfog[0], bfog[1], bfog[2], bfog[3]);                          // kf0
        SECIMG(afo1, bfog[0] + d64, bfog[1] + d64, bfog[2] + d64, bfog[3] + d64);  // kf1
        SEC(afo0 + 128, W20, W21, W22, W23);                // kf2 (resident)
        SEC(afo1 + 128, W30, W31, W32, W33);                // kf3 (resident)
        VMW4(); SEC(afo0 + 256, X0, X1, X2, X3); ISS_X4();  // kf4 <- kfi2
        VMW4(); SEC(afo1 + 256, Y0, Y1, Y2, Y3); ISS_Y5();  // kf5 <- kfi3
        xaddr += 32768ull;
        ISS_XC();                                           // xc for t+1 (newest)
        VMW8(); SEC(afo0 + 384, X0, X1, X2, X3); ISS_X2();  // kf6 <- kfi4
        VMW8(); SEC(afo1 + 384, Y0, Y1, Y2, Y3); ISS_Y3();  // kf7 <- kfi5
        GATES_AND_BARRIER();
    }

    // ---------------- IDLE phase (win0 tail: zero input) ----------------
    const int is0 = s0 > a1 ? s0 : a1;
    if (is0 < se) {
        if (s0 >= a1) { ISS_X2(); ISS_Y3(); }   // idle-only chunk: prime [X,Y]=8
        float bs0 = bsum[16 * w + c16];
        float bs1 = bsum[256 + 16 * w + c16];
        float bs2 = bsum[512 + 16 * w + c16];
        float bs3 = bsum[768 + 16 * w + c16];
        for (int t = is0; t < se; ++t) {
            const char* rbp = lds + HB + (((t + 1) & 1) << 13);
            char* wbp = lds + HB + ((t & 1) << 13);
            f32x4 acc0 = {bs0, bs0, bs0, bs0};
            f32x4 acc1 = {bs1, bs1, bs1, bs1};
            f32x4 acc2 = {bs2, bs2, bs2, bs2};
            f32x4 acc3 = {bs3, bs3, bs3, bs3};
            SECIMG(afo0, bfog[0], bfog[1], bfog[2], bfog[3]);
            SECIMG(afo1, bfog[0] + d64, bfog[1] + d64, bfog[2] + d64, bfog[3] + d64);
            SEC(afo0 + 128, W20, W21, W22, W23);
            SEC(afo1 + 128, W30, W31, W32, W33);
            VMW4(); SEC(afo0 + 256, X0, X1, X2, X3); ISS_X4();
            VMW4(); SEC(afo1 + 256, Y0, Y1, Y2, Y3); ISS_Y5();
            VMW4(); SEC(afo0 + 384, X0, X1, X2, X3); ISS_X2();
            VMW4(); SEC(afo1 + 384, Y0, Y1, Y2, Y3); ISS_Y3();
            GATES_AND_BARRIER();
        }
    }

    if (se < 299) {
        const char* slot = lds + HB + (((se - 1) & 1) * 8192);
        *(f16x4*)(hstate + (size_t)wg * 8192 + tid * 8) = *(const f16x4*)(slot + tid * 8);
        float* cp = cstate + ((size_t)wg * 1024 + tid) * 4;
        float* pp = poolstate + ((size_t)wg * 1024 + tid) * 4;
#pragma unroll
        for (int i = 0; i < 4; i++) { cp[i] = cst[i]; pp[i] = pool[i]; }
    } else {
#pragma unroll
        for (int r = 0; r < 4; r++) {
            int m = 4 * quad + r;
            feat[(size_t)(sg * 16 + m) * 512 + win * 256 + 16 * w + c16] = pool[r];
        }
    }
}

// ---------------- K3: final FC ----------------
__global__ void k_fc(const float* __restrict__ feat, const float* __restrict__ Wfc,
                     const float* __restrict__ bfc, float* __restrict__ out)
{
    int b = blockIdx.x, c = threadIdx.x;
    if (c < 60) {
        const float4* fr = (const float4*)(feat + (size_t)b * 512);
        const float4* wr = (const float4*)(Wfc + (size_t)c * 512);
        float s = bfc[c];
        for (int k = 0; k < 128; k++) {
            float4 f = fr[k], ww = wr[k];
            s += f.x * ww.x + f.y * ww.y + f.z * ww.z + f.w * ww.w;
        }
        out[b * 60 + c] = s;
    }
}

extern "C" void kernel_launch(void* const* d_in, const int* in_sizes, int n_in,
                              void* d_out, int out_size, void* d_ws, size_t ws_size,
                              hipStream_t stream)
{
    const float* x   = (const float*)d_in[0];
    const float* Wih = (const float*)d_in[1];
    const float* Whh = (const float*)d_in[2];
    const float* bih = (const float*)d_in[3];
    const float* bhh = (const float*)d_in[4];
    const float* Wfc = (const float*)d_in[5];
    const float* bfc = (const float*)d_in[6];
    float* out = (float*)d_out;

    char* p = (char*)d_ws;
    f16* wlds    = (f16*)p;   p += 131072;
    f16* whhswz  = (f16*)p;   p += 393216;
    f16* wihswz  = (f16*)p;   p += 262144;
    float* bsum  = (float*)p; p += 4096;
    float* feat  = (float*)p; p += 524288;
    char* hstate = p;         p += 262144;
    float* cstate = (float*)p;    p += 524288;
    float* poolstate = (float*)p; p += 524288;
    f16* xp = (f16*)p;
    size_t fixed = (size_t)(p - (char*)d_ws);

    long long avail = (long long)ws_size - (long long)fixed - 65536;  // prefetch slack
    int CHT = (int)(avail / 524288);
    if (CHT < 1) CHT = 1;
    if (CHT > 299) CHT = 299;

    k_prep<<<196, 256, 0, stream>>>(Wih, Whh, bih, bhh, wlds, whhswz, wihswz, bsum);
    for (int cs = 0; cs < 299; cs += CHT) {
        int ce = cs + CHT; if (ce > 299) ce = 299;
        int nb = (ce - cs + 7) / 8;
        k_xproj<<<16 * nb, 1024, 0, stream>>>(x, wihswz, bsum, xp, cs, ce, CHT);
        k_lstm<<<32, 1024, 0, stream>>>(wlds, whhswz, bsum, xp, feat,
                                        hstate, cstate, poolstate, cs, ce, CHT);
    }
    k_fc<<<256, 64, 0, stream>>>(feat, Wfc, bfc, out);
}

// Round 17
// 915.925 us; speedup vs baseline: 1.7955x; 1.1987x over previous
//
#include <hip/hip_runtime.h>

#define T_ 300
#define C_ 128
#define HB 131072  // byte offset of h double-buffer in k_lstm LDS
#define L2E  1.4426950408889634f
#define L2E2 2.8853900817779268f

typedef _Float16 f16;
typedef _Float16 f16x8 __attribute__((ext_vector_type(8)));
typedef _Float16 f16x4 __attribute__((ext_vector_type(4)));
typedef _Float16 f16x2 __attribute__((ext_vector_type(2)));
typedef float f32x4 __attribute__((ext_vector_type(4)));

#define MFMA16(a, b, c) __builtin_amdgcn_mfma_f32_16x16x32_f16((a), (b), (c), 0, 0, 0)

#if __has_builtin(__builtin_amdgcn_exp2f)
#define EX2(x) __builtin_amdgcn_exp2f(x)
#else
#define EX2(x) exp2f(x)
#endif
#define RCPF(x) __builtin_amdgcn_rcpf(x)

// R12/R15-validated fast forms
__device__ __forceinline__ float sigm(float x) {
    return RCPF(1.f + EX2(-x * L2E));
}
__device__ __forceinline__ float tanhx(float x) {
    return __builtin_fmaf(-2.f, RCPF(1.f + EX2(x * L2E2)), 1.f);
}

// ---------------- K0: weight conversion / pre-swizzle (R9 verbatim) ----------------
__global__ void k_prep(const float* __restrict__ Wih, const float* __restrict__ Whh,
                       const float* __restrict__ bih, const float* __restrict__ bhh,
                       f16* __restrict__ wlds, f16* __restrict__ whhswz,
                       f16* __restrict__ wihswz, float* __restrict__ bsum)
{
    int i = blockIdx.x * 256 + threadIdx.x;
    if (i < 8192) {
        int col = i >> 3, k0 = (i & 7) * 8;
#pragma unroll
        for (int j = 0; j < 8; j++) wlds[col * 64 + k0 + j] = (f16)Whh[col * 256 + k0 + j];
    } else if (i < 32768) {
        // W_hh k64..256 pre-swizzled per (w16, g, kfi 0..5, lane)
        int q = i - 8192; int l = q & 63; q >>= 6;
        int kfi = q % 6; q /= 6;
        int g = q & 3, w16 = q >> 2;
        int col = g * 256 + 16 * w16 + (l & 15);
        int k = 64 + kfi * 32 + 8 * (l >> 4);
        f16* dst = whhswz + (((size_t)(w16 * 4 + g) * 6 + kfi) * 64 + l) * 8;
#pragma unroll
        for (int j = 0; j < 8; j++) dst[j] = (f16)Whh[col * 256 + k + j];
    } else if (i < 49152) {
        // W_ih k0..128 pre-swizzled per (w16, g, kfi 0..3, lane)
        int q = i - 32768; int l = q & 63; q >>= 6;
        int kfi = q & 3; q >>= 2;
        int g = q & 3, w16 = q >> 2;
        int col = g * 256 + 16 * w16 + (l & 15);
        int k = kfi * 32 + 8 * (l >> 4);
        f16* dst = wihswz + (((size_t)(w16 * 4 + g) * 4 + kfi) * 64 + l) * 8;
#pragma unroll
        for (int j = 0; j < 8; j++) dst[j] = (f16)Wih[col * 128 + k + j];
    } else if (i < 50176) {
        int j = i - 49152;
        bsum[j] = bih[j] + bhh[j];
    }
}

// ---------------- K1: x_proj precompute (R9 verbatim) ----------------
__global__ __launch_bounds__(1024)
__attribute__((amdgpu_waves_per_eu(4, 4)))
void k_xproj(const float* __restrict__ x, const f16* __restrict__ wihswz,
             const float* __restrict__ bsum, f16* __restrict__ xp,
             int cs, int ce, int CHT)
{
    __shared__ __align__(16) char sd[8192];
    const int tid = threadIdx.x, lane = tid & 63, w = tid >> 6;
    const int sg = blockIdx.x & 15, tb = blockIdx.x >> 4;
    const int c16 = lane & 15, quad = lane >> 4;
    int ss = cs + tb * 8;
    int sse = ss + 8; if (sse > ce) sse = ce;

    f16x8 wreg[16];
#pragma unroll
    for (int g = 0; g < 4; g++)
#pragma unroll
        for (int kfi = 0; kfi < 4; kfi++)
            wreg[g * 4 + kfi] = *(const f16x8*)(wihswz + (((size_t)(w * 4 + g) * 4 + kfi) * 64 + lane) * 8);

    float bs[4];
#pragma unroll
    for (int g = 0; g < 4; g++) bs[g] = bsum[g * 256 + 16 * w + c16];

    for (int s = ss; s < sse; s++) {
        int pb = (s & 1) * 4096;
        {
            int seq = tid >> 6, cb = (tid & 63) * 2;
            const float* xr = x + ((size_t)(sg * 16 + seq) * T_ + s) * C_ + cb;
            float a0 = xr[0], a1 = xr[1], b0 = xr[C_], b1 = xr[C_ + 1];
            f16x2 d2 = {(f16)(b0 - a0), (f16)(b1 - a1)};
            *(f16x2*)(sd + pb + ((seq * 256 + cb * 2) ^ ((seq & 7) << 4))) = d2;
        }
        __syncthreads();
        f32x4 a[4];
#pragma unroll
        for (int g = 0; g < 4; g++) a[g] = (f32x4){0.f, 0.f, 0.f, 0.f};
#pragma unroll
        for (int kf = 0; kf < 4; kf++) {
            f16x8 af = *(const f16x8*)(sd + pb + ((c16 * 256 + (kf * 32 + 8 * quad) * 2) ^ ((c16 & 7) << 4)));
#pragma unroll
            for (int g = 0; g < 4; g++) a[g] = MFMA16(af, wreg[g * 4 + kf], a[g]);
        }
        f16* ob = xp + (((size_t)sg * CHT + (s - cs)) * 16 + w) * 1024 + lane * 4;
#pragma unroll
        for (int g = 0; g < 4; g++) {
            f16x4 o = {(f16)(a[g].x + bs[g]), (f16)(a[g].y + bs[g]),
                       (f16)(a[g].z + bs[g]), (f16)(a[g].w + bs[g])};
            *(f16x4*)(ob + g * 256) = o;
        }
    }
}

// ---------------- K2: recurrence — R15 structure, stall-free section order ----------------
// Resident W2*/W3* (kfi0,1) drained pre-loop (outside the ledger). Streams kfi2..5.
// Key change vs R15: consume LAST-step-issued X/Y (kfi2/kfi3 -> kf4/kf5) FIRST
// (issue->wait distance >= 1 full step), then run the 4 VMEM-free sections
// (kf0..kf3) as a ~600cyc shadow over the freshly issued X4/Y5, then consume
// them. All waits stall-free in steady state. MFMA accumulation order-independent.
// Active ledger (queue oldest->newest, 4 loads per ISS):
//   top: [xc, X:kfi2, Y:kfi3]=12 ; VMW0_8 -> retire xc
//   VMW4 -> retire X ; SEC kf4 ; ISS_X4 -> [Y,X4]=8
//   VMW4 -> retire Y ; SEC kf5 ; ISS_Y5 -> [X4,Y5]=8
//   SECIMG kf0 ; SECIMG kf1 ; SEC kf2 ; SEC kf3   (no VMEM, ~600cyc)
//   ISS_XC (t+1)                      -> [X4,Y5,xc]=12
//   VMW8 -> retire X4 ; SEC kf6 ; ISS_X2 -> [Y5,xc,X2]=12
//   VMW8 -> retire Y5 ; SEC kf7 ; ISS_Y3 -> [xc,X2,Y3]=12  (= top)
#define VMW8()   asm volatile("s_waitcnt vmcnt(8)");  __builtin_amdgcn_sched_barrier(0x186);
#define VMW4()   asm volatile("s_waitcnt vmcnt(4)");  __builtin_amdgcn_sched_barrier(0x186);
#define VMW0_8() asm volatile("s_waitcnt vmcnt(8)");  __builtin_amdgcn_sched_barrier(0);
#define GL(dst, voff, IMM) asm volatile("global_load_dwordx4 %0, %1, %2 offset:" IMM : "=v"(dst) : "v"(voff), "s"(wsz))
#define GLR(dst, voff, IMM) asm volatile("global_load_dwordx4 %0, %1, %2 offset:" IMM : "=&v"(dst) : "v"(voff), "s"(wsz))
#define GLX(dst, IMM)      asm volatile("global_load_dwordx2 %0, %1, off offset:" IMM : "=v"(dst) : "v"(xaddr))
#define ISS_X2() GL(X0,voffB0,"0");    GL(X1,voffB1,"0");    GL(X2,voffB2,"0");    GL(X3,voffB3,"0")
#define ISS_Y3() GL(Y0,voffB0,"1024"); GL(Y1,voffB1,"1024"); GL(Y2,voffB2,"1024"); GL(Y3,voffB3,"1024")
#define ISS_X4() GL(X0,voffB0,"2048"); GL(X1,voffB1,"2048"); GL(X2,voffB2,"2048"); GL(X3,voffB3,"2048")
#define ISS_Y5() GL(Y0,voffB0,"3072"); GL(Y1,voffB1,"3072"); GL(Y2,voffB2,"3072"); GL(Y3,voffB3,"3072")
#define ISS_XC() GLX(xv0,"0"); GLX(xv1,"512"); GLX(xv2,"1024"); GLX(xv3,"1536")
#define SEC(AFO, B0,B1,B2,B3) { f16x8 af = *(const f16x8*)(rbp + (AFO)); \
    acc0 = MFMA16(af, B0, acc0); acc1 = MFMA16(af, B1, acc1); \
    acc2 = MFMA16(af, B2, acc2); acc3 = MFMA16(af, B3, acc3); }
#define SECIMG(AFO, O0,O1,O2,O3) { f16x8 af = *(const f16x8*)(rbp + (AFO)); \
    { f16x8 b = *(const f16x8*)(lds + (O0)); acc0 = MFMA16(af, b, acc0); } \
    { f16x8 b = *(const f16x8*)(lds + (O1)); acc1 = MFMA16(af, b, acc1); } \
    { f16x8 b = *(const f16x8*)(lds + (O2)); acc2 = MFMA16(af, b, acc2); } \
    { f16x8 b = *(const f16x8*)(lds + (O3)); acc3 = MFMA16(af, b, acc3); } }
#define GATES_AND_BARRIER() \
        { \
            _Pragma("unroll") \
            for (int r = 0; r < 4; r++) { \
                float gi = acc0[r], gf = acc1[r], gg = acc2[r], go = acc3[r]; \
                float c_ = sigm(gf) * cst[r] + sigm(gi) * tanhx(gg); \
                cst[r] = c_; \
                float h_ = sigm(go) * tanhx(c_); \
                pool[r] += h_; \
                *(f16*)(wbp + hwo[r]) = (f16)h_; \
            } \
        } \
        asm volatile("s_waitcnt lgkmcnt(0)\n\ts_barrier" ::: "memory");

__global__ __launch_bounds__(1024)
__attribute__((amdgpu_waves_per_eu(4, 4)))
void k_lstm(const f16* __restrict__ wlds_src, const f16* __restrict__ whhswz,
            const float* __restrict__ bsum, const f16* __restrict__ xp,
            float* __restrict__ feat, char* __restrict__ hstate,
            float* __restrict__ cstate, float* __restrict__ poolstate,
            int cs, int ce, int CHT)
{
    __shared__ __align__(16) char lds[147456];
    const int tid = threadIdx.x, lane = tid & 63, w = tid >> 6;
    const int wg = blockIdx.x, win = wg >> 4, sg = wg & 15;
    const int c16 = lane & 15, quad = lane >> 4;
    const int a1 = win ? 299 : 154;
    const int t0 = win ? 145 : 0;
    int s0 = cs > t0 ? cs : t0;
    const int se = ce < 299 ? ce : 299;
    if (s0 >= se) return;
    const bool init = (s0 == t0);
    const f16* wsz = whhswz;

    // fragment addresses: frag(w,g,kfi) at (w*4+g)*6144 + kfi*1024 + lane*16
    unsigned voffA0 = (unsigned)((w * 4 + 0) * 6144 + lane * 16);
    unsigned voffA1 = (unsigned)((w * 4 + 1) * 6144 + lane * 16);
    unsigned voffA2 = (unsigned)((w * 4 + 2) * 6144 + lane * 16);
    unsigned voffA3 = (unsigned)((w * 4 + 3) * 6144 + lane * 16);
    unsigned voffB0 = voffA0 + 2048, voffB1 = voffA1 + 2048;   // kfi2 base
    unsigned voffB2 = voffA2 + 2048, voffB3 = voffA3 + 2048;

    // resident W_hh kfi0,1 (k64..128): issued now, drained by vmcnt(0) below,
    // so they never enter the counted in-loop ledger. Earlyclobber outputs.
    f16x8 W20, W21, W22, W23, W30, W31, W32, W33;
    GLR(W20, voffA0, "0");    GLR(W21, voffA1, "0");
    GLR(W22, voffA2, "0");    GLR(W23, voffA3, "0");
    GLR(W30, voffA0, "1024"); GLR(W31, voffA1, "1024");
    GLR(W32, voffA2, "1024"); GLR(W33, voffA3, "1024");

    // stage W k<64 image (swizzled)
    {
        int col = tid;
#pragma unroll
        for (int kb = 0; kb < 8; kb++) {
            f16x8 v = *(const f16x8*)(wlds_src + col * 64 + kb * 8);
            int byte = (col * 128 + kb * 16) ^ ((col & 7) << 4);
            *(f16x8*)(lds + byte) = v;
        }
    }
    // restore / zero h read-slot for step s0
    {
        char* slot = lds + HB + (((s0 - 1) & 1) * 8192);
        if (init) {
            f16x4 z = {0, 0, 0, 0};
            *(f16x4*)(slot + tid * 8) = z;
        } else {
            *(f16x4*)(slot + tid * 8) = *(const f16x4*)(hstate + (size_t)wg * 8192 + tid * 8);
        }
    }

    float cst[4], pool[4];
    if (init) {
#pragma unroll
        for (int i = 0; i < 4; i++) { cst[i] = 0.f; pool[i] = 0.f; }
    } else {
        const float* cp = cstate + ((size_t)wg * 1024 + tid) * 4;
        const float* pp = poolstate + ((size_t)wg * 1024 + tid) * 4;
#pragma unroll
        for (int i = 0; i < 4; i++) { cst[i] = cp[i]; pool[i] = pp[i]; }
    }

    // loop-invariant offsets (XOR algebra verified R14/R15):
    const int aswz = (c16 & 7) << 4;
    const int d64 = (aswz & 0x40) ? -64 : 64;
    const int afo0 = (c16 * 512 + 16 * quad) ^ aswz;
    const int afo1 = afo0 + d64;
    int bfog[4];
#pragma unroll
    for (int g = 0; g < 4; g++)
        bfog[g] = ((g * 256 + 16 * w + c16) * 128 + 16 * quad) ^ aswz;
    int hwo[4];
#pragma unroll
    for (int r = 0; r < 4; r++) {
        int m = 4 * quad + r;
        hwo[r] = (m * 512 + (16 * w + c16) * 2) ^ ((m & 7) << 4);
    }

    unsigned long long xaddr = (unsigned long long)xp
        + (((unsigned long long)sg * CHT + (unsigned)(s0 - cs)) * 16 + (unsigned)w) * 2048ull
        + (unsigned)lane * 8ull;

    f16x8 X0, X1, X2, X3, Y0, Y1, Y2, Y3;
    f16x4 xv0, xv1, xv2, xv3;

    // drain resident loads + LDS staging before the pipelined loop
    asm volatile("s_waitcnt vmcnt(0)");
    __builtin_amdgcn_sched_barrier(0);
    __syncthreads();

    const int ae = se < a1 ? se : a1;   // active end
    if (s0 < a1) { ISS_XC(); ISS_X2(); ISS_Y3(); }   // [xc,X,Y]=12

    // ---------------- ACTIVE phase ----------------
    for (int t = s0; t < ae; ++t) {
        const char* rbp = lds + HB + (((t + 1) & 1) << 13);
        char* wbp = lds + HB + ((t & 1) << 13);
        VMW0_8();   // retire xc for this step
        f32x4 acc0 = {(float)xv0.x, (float)xv0.y, (float)xv0.z, (float)xv0.w};
        f32x4 acc1 = {(float)xv1.x, (float)xv1.y, (float)xv1.z, (float)xv1.w};
        f32x4 acc2 = {(float)xv2.x, (float)xv2.y, (float)xv2.z, (float)xv2.w};
        f32x4 acc3 = {(float)xv3.x, (float)xv3.y, (float)xv3.z, (float)xv3.w};
        VMW4(); SEC(afo0 + 256, X0, X1, X2, X3); ISS_X4();  // kf4 <- kfi2 (issued last step)
        VMW4(); SEC(afo1 + 256, Y0, Y1, Y2, Y3); ISS_Y5();  // kf5 <- kfi3 (issued last step)
        SECIMG(afo0, bfog[0], bfog[1], bfog[2], bfog[3]);                          // kf0
        SECIMG(afo1, bfog[0] + d64, bfog[1] + d64, bfog[2] + d64, bfog[3] + d64);  // kf1
        SEC(afo0 + 128, W20, W21, W22, W23);                // kf2 (resident)
        SEC(afo1 + 128, W30, W31, W32, W33);                // kf3 (resident)
        xaddr += 32768ull;
        ISS_XC();                                           // xc for t+1 (newest)
        VMW8(); SEC(afo0 + 384, X0, X1, X2, X3); ISS_X2();  // kf6 <- kfi4 (~5 sections after issue)
        VMW8(); SEC(afo1 + 384, Y0, Y1, Y2, Y3); ISS_Y3();  // kf7 <- kfi5
        GATES_AND_BARRIER();
    }

    // ---------------- IDLE phase (win0 tail: zero input) ----------------
    const int is0 = s0 > a1 ? s0 : a1;
    if (is0 < se) {
        if (s0 >= a1) { ISS_X2(); ISS_Y3(); }   // idle-only chunk: prime [X,Y]=8
        float bs0 = bsum[16 * w + c16];
        float bs1 = bsum[256 + 16 * w + c16];
        float bs2 = bsum[512 + 16 * w + c16];
        float bs3 = bsum[768 + 16 * w + c16];
        for (int t = is0; t < se; ++t) {
            const char* rbp = lds + HB + (((t + 1) & 1) << 13);
            char* wbp = lds + HB + ((t & 1) << 13);
            f32x4 acc0 = {bs0, bs0, bs0, bs0};
            f32x4 acc1 = {bs1, bs1, bs1, bs1};
            f32x4 acc2 = {bs2, bs2, bs2, bs2};
            f32x4 acc3 = {bs3, bs3, bs3, bs3};
            VMW4(); SEC(afo0 + 256, X0, X1, X2, X3); ISS_X4();  // kf4 (first iter: also drains stale xc)
            VMW4(); SEC(afo1 + 256, Y0, Y1, Y2, Y3); ISS_Y5();  // kf5
            SECIMG(afo0, bfog[0], bfog[1], bfog[2], bfog[3]);
            SECIMG(afo1, bfog[0] + d64, bfog[1] + d64, bfog[2] + d64, bfog[3] + d64);
            SEC(afo0 + 128, W20, W21, W22, W23);
            SEC(afo1 + 128, W30, W31, W32, W33);
            VMW4(); SEC(afo0 + 384, X0, X1, X2, X3); ISS_X2();  // kf6
            VMW4(); SEC(afo1 + 384, Y0, Y1, Y2, Y3); ISS_Y3();  // kf7
            GATES_AND_BARRIER();
        }
    }

    if (se < 299) {
        const char* slot = lds + HB + (((se - 1) & 1) * 8192);
        *(f16x4*)(hstate + (size_t)wg * 8192 + tid * 8) = *(const f16x4*)(slot + tid * 8);
        float* cp = cstate + ((size_t)wg * 1024 + tid) * 4;
        float* pp = poolstate + ((size_t)wg * 1024 + tid) * 4;
#pragma unroll
        for (int i = 0; i < 4; i++) { cp[i] = cst[i]; pp[i] = pool[i]; }
    } else {
#pragma unroll
        for (int r = 0; r < 4; r++) {
            int m = 4 * quad + r;
            feat[(size_t)(sg * 16 + m) * 512 + win * 256 + 16 * w + c16] = pool[r];
        }
    }
}

// ---------------- K3: final FC ----------------
__global__ void k_fc(const float* __restrict__ feat, const float* __restrict__ Wfc,
                     const float* __restrict__ bfc, float* __restrict__ out)
{
    int b = blockIdx.x, c = threadIdx.x;
    if (c < 60) {
        const float4* fr = (const float4*)(feat + (size_t)b * 512);
        const float4* wr = (const float4*)(Wfc + (size_t)c * 512);
        float s = bfc[c];
        for (int k = 0; k < 128; k++) {
            float4 f = fr[k], ww = wr[k];
            s += f.x * ww.x + f.y * ww.y + f.z * ww.z + f.w * ww.w;
        }
        out[b * 60 + c] = s;
    }
}

extern "C" void kernel_launch(void* const* d_in, const int* in_sizes, int n_in,
                              void* d_out, int out_size, void* d_ws, size_t ws_size,
                              hipStream_t stream)
{
    const float* x   = (const float*)d_in[0];
    const float* Wih = (const float*)d_in[1];
    const float* Whh = (const float*)d_in[2];
    const float* bih = (const float*)d_in[3];
    const float* bhh = (const float*)d_in[4];
    const float* Wfc = (const float*)d_in[5];
    const float* bfc = (const float*)d_in[6];
    float* out = (float*)d_out;

    char* p = (char*)d_ws;
    f16* wlds    = (f16*)p;   p += 131072;
    f16* whhswz  = (f16*)p;   p += 393216;
    f16* wihswz  = (f16*)p;   p += 262144;
    float* bsum  = (float*)p; p += 4096;
    float* feat  = (float*)p; p += 524288;
    char* hstate = p;         p += 262144;
    float* cstate = (float*)p;    p += 524288;
    float* poolstate = (float*)p; p += 524288;
    f16* xp = (f16*)p;
    size_t fixed = (size_t)(p - (char*)d_ws);

    long long avail = (long long)ws_size - (long long)fixed - 65536;  // prefetch slack
    int CHT = (int)(avail / 524288);
    if (CHT < 1) CHT = 1;
    if (CHT > 299) CHT = 299;

    k_prep<<<196, 256, 0, stream>>>(Wih, Whh, bih, bhh, wlds, whhswz, wihswz, bsum);
    for (int cs = 0; cs < 299; cs += CHT) {
        int ce = cs + CHT; if (ce > 299) ce = 299;
        int nb = (ce - cs + 7) / 8;
        k_xproj<<<16 * nb, 1024, 0, stream>>>(x, wihswz, bsum, xp, cs, ce, CHT);
        k_lstm<<<32, 1024, 0, stream>>>(wlds, whhswz, bsum, xp, feat,
                                        hstate, cstate, poolstate, cs, ce, CHT);
    }
    k_fc<<<256, 64, 0, stream>>>(feat, Wfc, bfc, out);
}